// Round 2
// baseline (191.028 us; speedup 1.0000x reference)
//
#include <hip/hip_runtime.h>

// Axial 7x7 attention, fused. Shapes (fixed by reference):
//   N=512, GRID=7, Cq=64, Cv=512, B=N*7=3584
//   qH,qW: (B,7,64)  kH,kW: (B,64,7)  vH,vW: (B,512,7)
//   out: (N,512,7,7) fp32
// R2: barrier-free phase D via per-wave c-ownership + shfl row distribution.

#define NEGINF (-1e20f)

constexpr int QK_SLICE = 7 * 7 * 64;    // 3136 floats per n per q/k array
constexpr int V_SLICE  = 7 * 512 * 7;   // 25088 floats per n per v array / out

// LDS (floats): qHs 49x68 (3332) | kHs 7x456 (3192) | qWs | kWs | P 49x16 (784)
// total 13832 floats = 55.3 KB -> 2 blocks/CU
__global__ __launch_bounds__(512, 4) void fused_axial(
    const float* __restrict__ qH, const float* __restrict__ kH,
    const float* __restrict__ vH, const float* __restrict__ qW,
    const float* __restrict__ kW, const float* __restrict__ vW,
    float* __restrict__ out)
{
    __shared__ float sm[13832];
    float* qHs = sm;
    float* kHs = sm + 3332;
    float* qWs = sm + 6524;
    float* kWs = sm + 9856;
    float* P   = sm + 13048;

    const int n = blockIdx.x;
    const int t = threadIdx.x;

    // ---- Phase A: stage q/k slices (coalesced float4) ----
    {
        const float* srcQH = qH + n * QK_SLICE;
        const float* srcKH = kH + n * QK_SLICE;
        const float* srcQW = qW + n * QK_SLICE;
        const float* srcKW = kW + n * QK_SLICE;
        for (int it = t; it < 784; it += 512) {        // 784 float4 per array
            int wh = it >> 4;                          // q: flat = wh*64 + c
            int c  = (it & 15) << 2;
            float4 v0 = ((const float4*)srcQH)[it];
            *(float4*)(qHs + wh * 68 + c) = v0;
            float4 v1 = ((const float4*)srcQW)[it];
            *(float4*)(qWs + wh * 68 + c) = v1;
            int w = it / 112;                          // k: flat = w*448 + r
            int r = (it - w * 112) << 2;
            float4 v2 = ((const float4*)srcKH)[it];
            *(float4*)(kHs + w * 456 + r) = v2;
            float4 v3 = ((const float4*)srcKW)[it];
            *(float4*)(kWs + w * 456 + r) = v3;
        }
    }
    __syncthreads();

    // ---- Phase B: 686 dot products (len 64) -> logits in P ----
    for (int d = t; d < 686; d += 512) {
        const bool isH = d < 343;
        int dd = isH ? d : d - 343;
        int a   = dd / 49;            // H: w   W: h
        int rem = dd - a * 49;
        int b   = rem / 7;            // H: h   W: w
        int j   = rem - b * 7;
        const float* qrow  = (isH ? qHs : qWs) + (a * 7 + b) * 68;
        const float* kbase = (isH ? kHs : kWs) + a * 456 + j;
        float e = 0.f;
        #pragma unroll
        for (int c = 0; c < 64; c += 4) {
            float4 qv = *(const float4*)(qrow + c);
            e += qv.x * kbase[c * 7];
            e += qv.y * kbase[c * 7 + 7];
            e += qv.z * kbase[c * 7 + 14];
            e += qv.w * kbase[c * 7 + 21];
        }
        if (isH) {
            if (b == j) e = NEGINF;               // diagonal mask on eH(h==j)
            P[(b * 7 + a) * 16 + j] = e;          // logits[n,h,w,j]
        } else {
            P[(a * 7 + b) * 16 + 7 + j] = e;      // logits[n,h,w,7+y]
        }
    }
    __syncthreads();

    // ---- Phase C: softmax over 14 per (h,w) ----
    if (t < 49) {
        float* row = P + t * 16;
        float l[14];
        float m = -3.4e38f;
        #pragma unroll
        for (int k = 0; k < 14; ++k) { l[k] = row[k]; m = fmaxf(m, l[k]); }
        float s = 0.f;
        #pragma unroll
        for (int k = 0; k < 14; ++k) { l[k] = __expf(l[k] - m); s += l[k]; }
        float inv = 1.f / s;
        #pragma unroll
        for (int k = 0; k < 14; ++k) row[k] = l[k] * inv;
    }
    __syncthreads();

    // ---- Phase D: barrier-free. Wave wv owns c in [wv*64, wv*64+64).
    // out[n,c,h,w] = sum_j p[hw][j]*vH[n,w,c,j] + p[hw][7+j]*vW[n,h,c,j]
    const int wv   = t >> 6;
    const int lane = t & 63;
    const int hwc  = lane < 49 ? lane : 48;   // clamp so all lanes run shfl
    const int h    = hwc / 7;
    const int w    = hwc - h * 7;

    float pr[14];
    #pragma unroll
    for (int k = 0; k < 14; ++k) pr[k] = P[hwc * 16 + k];

    const float* vHn = vH + n * V_SLICE;
    const float* vWn = vW + n * V_SLICE;
    float* outn = out + n * V_SLICE;

    const int wl  = lane >> 3;        // source-lane layout: lane = wl*8 + cgp
    const int cgp = lane & 7;         // holds rows for c = c0+2*cgp, c0+2*cgp+1

    for (int chunk = 0; chunk < 4; ++chunk) {
        const int c0 = wv * 64 + chunk * 16;
        float vh[14], vw[14];
        if (lane < 56) {
            const float* pHrow = vHn + wl * 3584 + (c0 + 2 * cgp) * 7;
            const float* pWrow = vWn + wl * 3584 + (c0 + 2 * cgp) * 7;
            #pragma unroll
            for (int r = 0; r < 7; ++r) {           // 14 contiguous floats, 8B-aligned
                float2 a = *(const float2*)(pHrow + 2 * r);
                vh[2 * r] = a.x; vh[2 * r + 1] = a.y;
                float2 b = *(const float2*)(pWrow + 2 * r);
                vw[2 * r] = b.x; vw[2 * r + 1] = b.y;
            }
        }
        #pragma unroll
        for (int cg = 0; cg < 16; ++cg) {
            const int srcH = w * 8 + (cg >> 1);     // lane holding vH row (w, c0+cg)
            const int srcW = h * 8 + (cg >> 1);     // lane holding vW row (h, c0+cg)
            const int ro   = (cg & 1) * 7;          // which half of the 14 regs
            float acc = 0.f;
            #pragma unroll
            for (int j = 0; j < 7; ++j)
                acc += pr[j] * __shfl(vh[ro + j], srcH);
            #pragma unroll
            for (int j = 0; j < 7; ++j)
                acc += pr[7 + j] * __shfl(vw[ro + j], srcW);
            if (lane < 49)
                outn[(c0 + cg) * 49 + lane] = acc;  // 49 contiguous dwords/wave
        }
    }
}

extern "C" void kernel_launch(void* const* d_in, const int* in_sizes, int n_in,
                              void* d_out, int out_size, void* d_ws, size_t ws_size,
                              hipStream_t stream) {
    const float* qH = (const float*)d_in[0];
    const float* kH = (const float*)d_in[1];
    const float* vH = (const float*)d_in[2];
    const float* qW = (const float*)d_in[3];
    const float* kW = (const float*)d_in[4];
    const float* vW = (const float*)d_in[5];
    float* out = (float*)d_out;
    fused_axial<<<512, 512, 0, stream>>>(qH, kH, vH, qW, kW, vW, out);
}